// Round 7
// baseline (266.690 us; speedup 1.0000x reference)
//
#include <hip/hip_runtime.h>

typedef __attribute__((ext_vector_type(8))) short short8;
typedef __attribute__((ext_vector_type(4))) short s16x4;
typedef __attribute__((ext_vector_type(8))) __bf16 bf16x8;
typedef __attribute__((ext_vector_type(4))) __bf16 bf16x4;
typedef __attribute__((ext_vector_type(4))) float f32x4;
typedef __attribute__((ext_vector_type(4))) unsigned uint4v;
typedef __attribute__((ext_vector_type(2))) unsigned uint2v;

__device__ inline f32x4 mfma_bf16(short8 a, short8 b, f32x4 c) {
    return __builtin_amdgcn_mfma_f32_16x16x32_bf16(
        __builtin_bit_cast(bf16x8, a), __builtin_bit_cast(bf16x8, b), c, 0, 0, 0);
}
// K=16 bf16 MFMA: A-frag layout A[m=l16][k=quad*4+j] == C/D layout of a prior
// MFMA transposed -> P needs no layout transform.
__device__ inline f32x4 mfma16(uint2v a, uint2v b, f32x4 c) {
#if __has_builtin(__builtin_amdgcn_mfma_f32_16x16x16_bf16)
    return __builtin_amdgcn_mfma_f32_16x16x16_bf16(
        __builtin_bit_cast(bf16x4, a), __builtin_bit_cast(bf16x4, b), c, 0, 0, 0);
#else
    return __builtin_amdgcn_mfma_f32_16x16x16bf16_1k(
        __builtin_bit_cast(s16x4, a), __builtin_bit_cast(s16x4, b), c, 0, 0, 0);
#endif
}

// round-to-nearest-even fp32 -> bf16 bits
__device__ inline unsigned f2b_u(float f) {
    unsigned u = __float_as_uint(f);
    return (u + 0x7fffu + ((u >> 16) & 1u)) >> 16;
}
__device__ inline short f2b(float f) { return (short)f2b_u(f); }
__device__ inline unsigned pkbf(float a, float b) {
    return f2b_u(a) | (f2b_u(b) << 16);
}

__device__ inline short8 ld8(const short* p) { return *(const short8*)p; }
__device__ inline short8 ld8(const float* p) {
    f32x4 a = *(const f32x4*)p;
    f32x4 b = *(const f32x4*)(p + 4);
    uint4v q;
    q[0] = pkbf(a[0], a[1]); q[1] = pkbf(a[2], a[3]);
    q[2] = pkbf(b[0], b[1]); q[3] = pkbf(b[2], b[3]);
    return __builtin_bit_cast(short8, q);
}
__device__ inline void storeC(short* C, size_t i, float v) { C[i] = f2b(v); }
__device__ inline void storeC(float* C, size_t i, float v) { C[i] = v; }

// log2(e)/32 : folded into Q so softmax uses exp2 (bare v_exp_f32)
#define QSCALE 0.04508422052265167f

// ---------------------------------------------------------------------------
// W [K][N] fp32 row-major -> Wt [N][K] bf16 k-major. grid (N/64, K/64).
// ---------------------------------------------------------------------------
__global__ __launch_bounds__(256) void transpose_w(
    const float* __restrict__ W, short* __restrict__ Wt, int K, int N)
{
    __shared__ short T[64 * 72];
    const int tid = threadIdx.x;
    const int n0 = blockIdx.x * 64, k0 = blockIdx.y * 64;
    {
        const int kl = tid >> 2, nc = (tid & 3) * 16;
        const float* src = W + (size_t)(k0 + kl) * N + n0 + nc;
        float v[16];
        *(f32x4*)&v[0]  = *(const f32x4*)(src + 0);
        *(f32x4*)&v[4]  = *(const f32x4*)(src + 4);
        *(f32x4*)&v[8]  = *(const f32x4*)(src + 8);
        *(f32x4*)&v[12] = *(const f32x4*)(src + 12);
        #pragma unroll
        for (int j = 0; j < 16; ++j) T[(nc + j) * 72 + kl] = f2b(v[j]);
    }
    __syncthreads();
    {
        const int nl = tid >> 2, kc = (tid & 3) * 16;
        short8 w0 = *(const short8*)&T[nl * 72 + kc];
        short8 w1 = *(const short8*)&T[nl * 72 + kc + 8];
        short* dst = Wt + (size_t)(n0 + nl) * K + k0 + kc;
        *(short8*)dst = w0;
        *(short8*)(dst + 8) = w1;
    }
}

// ---------------------------------------------------------------------------
// V transpose: qkv (B*N,3072) bf16 cols 2048+h*64 -> vt[(b*16+h)][dim][2048].
// ---------------------------------------------------------------------------
__global__ __launch_bounds__(256) void vtrans(
    const short* __restrict__ qkv, short* __restrict__ vt)
{
    __shared__ short T[64 * 72];
    const int tid = threadIdx.x;
    const int nt = blockIdx.x * 64, bh = blockIdx.y;
    const int b = bh >> 4, h = bh & 15;
    {
        const int tok = tid >> 2, dc = (tid & 3) * 16;
        const short* src = qkv + ((size_t)b * 2048 + nt + tok) * 3072 + 2048 + h * 64 + dc;
        short8 v0 = *(const short8*)src;
        short8 v1 = *(const short8*)(src + 8);
        #pragma unroll
        for (int j = 0; j < 8; ++j) {
            T[(dc + j) * 72 + tok]     = v0[j];
            T[(dc + 8 + j) * 72 + tok] = v1[j];
        }
    }
    __syncthreads();
    {
        const int dim = tid >> 2, kc = (tid & 3) * 16;
        short8 w0 = *(const short8*)&T[dim * 72 + kc];
        short8 w1 = *(const short8*)&T[dim * 72 + kc + 8];
        short* dst = vt + ((size_t)bh * 64 + dim) * 2048 + nt + kc;
        *(short8*)dst = w0;
        *(short8*)(dst + 8) = w1;
    }
}

// ---------------------------------------------------------------------------
// GEMM with register-prefetch double buffering. C = A @ Bt^T (+bias).
// 128x128 tile, BK=32, 4 waves 2x2, each 64x64 via 4x4 MFMA.
// QSC: scale cols<1024 by log2(e)/32 (Q pre-scale for exp2 softmax).
// ---------------------------------------------------------------------------
template <typename TA, bool QSC, bool ADD_BIAS, typename TC>
__global__ __launch_bounds__(256) void gemm128(
    const TA* __restrict__ A, const short* __restrict__ Bt,
    const float* __restrict__ bias, TC* __restrict__ C,
    int M, int N, int K, int lda)
{
    __shared__ short A_s[128 * 40];
    __shared__ short B_s[128 * 40];
    const int tid  = threadIdx.x;
    const int lane = tid & 63;
    const int wave = tid >> 6;
    const int quad = lane >> 4;
    const int l16  = lane & 15;
    const int wr   = wave >> 1;
    const int wc   = wave & 1;
    const int bm   = blockIdx.y * 128;
    const int bn   = blockIdx.x * 128;

    f32x4 acc[4][4];
    #pragma unroll
    for (int i = 0; i < 4; ++i)
        #pragma unroll
        for (int j = 0; j < 4; ++j)
            acc[i][j] = f32x4{0.f, 0.f, 0.f, 0.f};

    const int s_row = tid >> 1;           // 0..127
    const int s_k   = (tid & 1) * 16;     // 0,16
    const TA*    ap = A  + (size_t)(bm + s_row) * lda + s_k;
    const short* bp = Bt + (size_t)(bn + s_row) * K   + s_k;

    short8 pa0 = ld8(ap), pa1 = ld8(ap + 8);
    short8 pb0 = *(const short8*)bp, pb1 = *(const short8*)(bp + 8);

    for (int k0 = 0; k0 < K; k0 += 32) {
        __syncthreads();
        *(short8*)&A_s[s_row * 40 + s_k]     = pa0;
        *(short8*)&A_s[s_row * 40 + s_k + 8] = pa1;
        *(short8*)&B_s[s_row * 40 + s_k]     = pb0;
        *(short8*)&B_s[s_row * 40 + s_k + 8] = pb1;
        if (k0 + 32 < K) {
            pa0 = ld8(ap + k0 + 32);
            pa1 = ld8(ap + k0 + 40);
            pb0 = *(const short8*)(bp + k0 + 32);
            pb1 = *(const short8*)(bp + k0 + 40);
        }
        __syncthreads();

        short8 a[4], b[4];
        #pragma unroll
        for (int i = 0; i < 4; ++i)
            a[i] = *(const short8*)&A_s[(wr * 64 + i * 16 + l16) * 40 + quad * 8];
        #pragma unroll
        for (int j = 0; j < 4; ++j)
            b[j] = *(const short8*)&B_s[(wc * 64 + j * 16 + l16) * 40 + quad * 8];
        #pragma unroll
        for (int i = 0; i < 4; ++i)
            #pragma unroll
            for (int j = 0; j < 4; ++j)
                acc[i][j] = mfma_bf16(a[i], b[j], acc[i][j]);
    }

    const float scale = (QSC && bn < 1024) ? QSCALE : 1.0f;
    #pragma unroll
    for (int i = 0; i < 4; ++i) {
        #pragma unroll
        for (int j = 0; j < 4; ++j) {
            #pragma unroll
            for (int r = 0; r < 4; ++r) {
                int row = bm + wr * 64 + i * 16 + quad * 4 + r;
                int col = bn + wc * 64 + j * 16 + l16;
                float v = acc[i][j][r] * scale;
                if (ADD_BIAS) v += bias[col];
                storeC(C, (size_t)row * N + col, v);
            }
        }
    }
}

// ---------------------------------------------------------------------------
// Flash attention v4: S^T (swapped-operand) MFMA -> exp2 -> pack -> PV via
// K=16 MFMA whose A-frag layout equals the S^T C-layout: NO P LDS roundtrip.
// V in LDS as [key-group-of-8][dim][k&7] (group stride 520 shorts) -> aligned
// b64 B-frag reads, 2-way (free) conflicts. 4 blocks/CU (35KB LDS, lb(256,4)).
// ctx written in-place over q columns. grid (2048/64, 32) = 1024 blocks.
// ---------------------------------------------------------------------------
__global__ __launch_bounds__(256, 4) void attn128(
    short* __restrict__ qkv, const short* __restrict__ vt)
{
    __shared__ short Ks[128 * 72];   // [key][dim]
    __shared__ short Vs[16 * 520];   // [g][dim][k&7], g = key>>3 (tile-local)

    const int tid  = threadIdx.x;
    const int lane = tid & 63;
    const int wave = tid >> 6;
    const int quad = lane >> 4;
    const int l16  = lane & 15;
    const int bh   = blockIdx.y, b = bh >> 4, h = bh & 15;
    const int qb   = blockIdx.x * 64;
    const size_t rowbase = (size_t)b * 2048;

    // Q fragments (B-op for S^T: n=l16, k=quad*8+j), pre-scaled by log2e/32
    short8 aq0, aq1;
    {
        const short* qp = qkv + (rowbase + qb + wave * 16 + l16) * 3072 + h * 64;
        aq0 = *(const short8*)(qp + quad * 8);
        aq1 = *(const short8*)(qp + 32 + quad * 8);
    }

    f32x4 o[4];
    #pragma unroll
    for (int c = 0; c < 4; ++c) o[c] = f32x4{0.f, 0.f, 0.f, 0.f};
    float rsum = 0.f;   // softmax denom partial for q = l16

    const int kkey = tid >> 1, kdc = (tid & 1) * 32;
    const int vdim = tid >> 2, vg0 = (tid & 3) * 4;    // 4 key-groups per lane
    const short* kbase = qkv + (rowbase + kkey) * 3072 + 1024 + h * 64 + kdc;
    const short* vbase = vt + ((size_t)bh * 64 + vdim) * 2048 + vg0 * 8;

    // prefetch tile 0
    short8 kr0 = *(const short8*)(kbase);
    short8 kr1 = *(const short8*)(kbase + 8);
    short8 kr2 = *(const short8*)(kbase + 16);
    short8 kr3 = *(const short8*)(kbase + 24);
    short8 vr0 = *(const short8*)(vbase);
    short8 vr1 = *(const short8*)(vbase + 8);
    short8 vr2 = *(const short8*)(vbase + 16);
    short8 vr3 = *(const short8*)(vbase + 24);

    for (int kt = 0; kt < 2048; kt += 128) {
        __syncthreads();                      // prior-tile LDS readers done
        *(short8*)&Ks[kkey * 72 + kdc]      = kr0;
        *(short8*)&Ks[kkey * 72 + kdc + 8]  = kr1;
        *(short8*)&Ks[kkey * 72 + kdc + 16] = kr2;
        *(short8*)&Ks[kkey * 72 + kdc + 24] = kr3;
        *(short8*)&Vs[(vg0 + 0) * 520 + vdim * 8] = vr0;
        *(short8*)&Vs[(vg0 + 1) * 520 + vdim * 8] = vr1;
        *(short8*)&Vs[(vg0 + 2) * 520 + vdim * 8] = vr2;
        *(short8*)&Vs[(vg0 + 3) * 520 + vdim * 8] = vr3;
        if (kt + 128 < 2048) {                // prefetch next tile
            const short* kp = kbase + (size_t)(kt + 128) * 3072;
            kr0 = *(const short8*)(kp);
            kr1 = *(const short8*)(kp + 8);
            kr2 = *(const short8*)(kp + 16);
            kr3 = *(const short8*)(kp + 24);
            const short* vp = vbase + kt + 128;
            vr0 = *(const short8*)(vp);
            vr1 = *(const short8*)(vp + 8);
            vr2 = *(const short8*)(vp + 16);
            vr3 = *(const short8*)(vp + 24);
        }
        __syncthreads();                      // tile visible

        // S^T: lane holds S[q=l16][key = c*16 + quad*4 + r]
        f32x4 st[8];
        #pragma unroll
        for (int c = 0; c < 8; ++c) {
            short8 ka0 = *(const short8*)&Ks[(c * 16 + l16) * 72 + quad * 8];
            short8 ka1 = *(const short8*)&Ks[(c * 16 + l16) * 72 + 32 + quad * 8];
            f32x4 z = f32x4{0.f, 0.f, 0.f, 0.f};
            z = mfma_bf16(ka0, aq0, z);
            st[c] = mfma_bf16(ka1, aq1, z);
        }

        // p = exp2(s'); pack straight into PV A-fragments (K=16 layout)
        uint2v pa[8];
        #pragma unroll
        for (int c = 0; c < 8; ++c) {
            float p0 = exp2f(st[c][0]);
            float p1 = exp2f(st[c][1]);
            float p2 = exp2f(st[c][2]);
            float p3 = exp2f(st[c][3]);
            rsum += (p0 + p1) + (p2 + p3);
            uint2v pk;
            pk[0] = pkbf(p0, p1);
            pk[1] = pkbf(p2, p3);
            pa[c] = pk;
        }

        // PV: O[q][dim] += P[q][key] V[key][dim], K=16 per MFMA
        #pragma unroll
        for (int c2 = 0; c2 < 4; ++c2) {
            #pragma unroll
            for (int c = 0; c < 8; ++c) {
                uint2v bv = *(const uint2v*)&Vs[(2 * c + (quad >> 1)) * 520
                                                + (c2 * 16 + l16) * 8
                                                + (quad & 1) * 4];
                o[c2] = mfma16(pa[c], bv, o[c2]);
            }
        }
    }

    // full denom for q=l16: sum over the 4 quad-lanes
    rsum += __shfl_xor(rsum, 16, 64);
    rsum += __shfl_xor(rsum, 32, 64);

    // epilogue: o rows are q=quad*4+r; fetch that q's denom from lane q
    #pragma unroll
    for (int r = 0; r < 4; ++r) {
        float inv = 1.0f / __shfl(rsum, quad * 4 + r, 64);
        size_t row = rowbase + qb + wave * 16 + quad * 4 + r;
        #pragma unroll
        for (int c2 = 0; c2 < 4; ++c2)
            qkv[row * 3072 + h * 64 + c2 * 16 + l16] = f2b(o[c2][r] * inv);
    }
}

// ---------------------------------------------------------------------------
extern "C" void kernel_launch(void* const* d_in, const int* in_sizes, int n_in,
                              void* d_out, int out_size, void* d_ws, size_t ws_size,
                              hipStream_t stream)
{
    const float* x    = (const float*)d_in[0];   // (2,2048,1024) fp32
    const float* Wqkv = (const float*)d_in[2];   // (1024,3072) fp32
    const float* Wout = (const float*)d_in[3];   // (1024,1024) fp32
    const float* bout = (const float*)d_in[4];   // (1024,) fp32
    float* out = (float*)d_out;                  // (2,2048,1024) fp32

    // ws: 32 MiB. qkv 24 MiB | 8 MiB region time-shared: Wqkvt -> vt -> Woutt
    short* qkv    = (short*)d_ws;                // 4096 x 3072 bf16
    short* vtbuf  = qkv + (size_t)4096 * 3072;   // 8 MiB region
    short* wqkvt  = vtbuf;                       // 3072 x 1024 bf16
    short* woutt  = vtbuf;                       // 1024 x 1024 bf16

    dim3 blk(256);
    transpose_w<<<dim3(48, 16), blk, 0, stream>>>(Wqkv, wqkvt, 1024, 3072);
    gemm128<float, true, false, short><<<dim3(24, 32), blk, 0, stream>>>(
        x, wqkvt, nullptr, qkv, 4096, 3072, 1024, 1024);
    vtrans<<<dim3(32, 32), blk, 0, stream>>>(qkv, vtbuf);
    attn128<<<dim3(32, 32), blk, 0, stream>>>(qkv, vtbuf);
    transpose_w<<<dim3(16, 16), blk, 0, stream>>>(Wout, woutt, 1024, 1024);
    gemm128<short, false, true, float><<<dim3(8, 32), blk, 0, stream>>>(
        qkv, woutt, bout, out, 4096, 1024, 1024, 3072);
}

// Round 8
// 239.454 us; speedup vs baseline: 1.1137x; 1.1137x over previous
//
#include <hip/hip_runtime.h>

typedef __attribute__((ext_vector_type(8))) short short8;
typedef __attribute__((ext_vector_type(4))) short s16x4;
typedef __attribute__((ext_vector_type(8))) __bf16 bf16x8;
typedef __attribute__((ext_vector_type(4))) __bf16 bf16x4;
typedef __attribute__((ext_vector_type(4))) float f32x4;
typedef __attribute__((ext_vector_type(4))) unsigned uint4v;
typedef __attribute__((ext_vector_type(2))) unsigned uint2v;

__device__ inline f32x4 mfma_bf16(short8 a, short8 b, f32x4 c) {
    return __builtin_amdgcn_mfma_f32_16x16x32_bf16(
        __builtin_bit_cast(bf16x8, a), __builtin_bit_cast(bf16x8, b), c, 0, 0, 0);
}
// K=16 bf16 MFMA: A-frag layout A[m=l16][k=quad*4+j] == C/D layout of a prior
// MFMA transposed -> P needs no layout transform.
__device__ inline f32x4 mfma16(uint2v a, uint2v b, f32x4 c) {
#if __has_builtin(__builtin_amdgcn_mfma_f32_16x16x16_bf16)
    return __builtin_amdgcn_mfma_f32_16x16x16_bf16(
        __builtin_bit_cast(bf16x4, a), __builtin_bit_cast(bf16x4, b), c, 0, 0, 0);
#else
    return __builtin_amdgcn_mfma_f32_16x16x16bf16_1k(
        __builtin_bit_cast(s16x4, a), __builtin_bit_cast(s16x4, b), c, 0, 0, 0);
#endif
}

// round-to-nearest-even fp32 -> bf16 bits
__device__ inline unsigned f2b_u(float f) {
    unsigned u = __float_as_uint(f);
    return (u + 0x7fffu + ((u >> 16) & 1u)) >> 16;
}
__device__ inline short f2b(float f) { return (short)f2b_u(f); }
__device__ inline unsigned pkbf(float a, float b) {
    return f2b_u(a) | (f2b_u(b) << 16);
}

__device__ inline short8 ld8(const short* p) { return *(const short8*)p; }
__device__ inline short8 ld8(const float* p) {
    f32x4 a = *(const f32x4*)p;
    f32x4 b = *(const f32x4*)(p + 4);
    uint4v q;
    q[0] = pkbf(a[0], a[1]); q[1] = pkbf(a[2], a[3]);
    q[2] = pkbf(b[0], b[1]); q[3] = pkbf(b[2], b[3]);
    return __builtin_bit_cast(short8, q);
}
__device__ inline void storeC(short* C, size_t i, float v) { C[i] = f2b(v); }
__device__ inline void storeC(float* C, size_t i, float v) { C[i] = v; }

// log2(e)/32 : folded into Q so softmax uses exp2 (bare v_exp_f32)
#define QSCALE 0.04508422052265167f

// ---------------------------------------------------------------------------
// W [K][N] fp32 row-major -> Wt [N][K] bf16 k-major. grid (N/64, K/64).
// ---------------------------------------------------------------------------
__global__ __launch_bounds__(256) void transpose_w(
    const float* __restrict__ W, short* __restrict__ Wt, int K, int N)
{
    __shared__ short T[64 * 72];
    const int tid = threadIdx.x;
    const int n0 = blockIdx.x * 64, k0 = blockIdx.y * 64;
    {
        const int kl = tid >> 2, nc = (tid & 3) * 16;
        const float* src = W + (size_t)(k0 + kl) * N + n0 + nc;
        float v[16];
        *(f32x4*)&v[0]  = *(const f32x4*)(src + 0);
        *(f32x4*)&v[4]  = *(const f32x4*)(src + 4);
        *(f32x4*)&v[8]  = *(const f32x4*)(src + 8);
        *(f32x4*)&v[12] = *(const f32x4*)(src + 12);
        #pragma unroll
        for (int j = 0; j < 16; ++j) T[(nc + j) * 72 + kl] = f2b(v[j]);
    }
    __syncthreads();
    {
        const int nl = tid >> 2, kc = (tid & 3) * 16;
        short8 w0 = *(const short8*)&T[nl * 72 + kc];
        short8 w1 = *(const short8*)&T[nl * 72 + kc + 8];
        short* dst = Wt + (size_t)(n0 + nl) * K + k0 + kc;
        *(short8*)dst = w0;
        *(short8*)(dst + 8) = w1;
    }
}

// ---------------------------------------------------------------------------
// V transpose: qkv (B*N,3072) bf16 cols 2048+h*64 -> vt[(b*16+h)][dim][2048].
// ---------------------------------------------------------------------------
__global__ __launch_bounds__(256) void vtrans(
    const short* __restrict__ qkv, short* __restrict__ vt)
{
    __shared__ short T[64 * 72];
    const int tid = threadIdx.x;
    const int nt = blockIdx.x * 64, bh = blockIdx.y;
    const int b = bh >> 4, h = bh & 15;
    {
        const int tok = tid >> 2, dc = (tid & 3) * 16;
        const short* src = qkv + ((size_t)b * 2048 + nt + tok) * 3072 + 2048 + h * 64 + dc;
        short8 v0 = *(const short8*)src;
        short8 v1 = *(const short8*)(src + 8);
        #pragma unroll
        for (int j = 0; j < 8; ++j) {
            T[(dc + j) * 72 + tok]     = v0[j];
            T[(dc + 8 + j) * 72 + tok] = v1[j];
        }
    }
    __syncthreads();
    {
        const int dim = tid >> 2, kc = (tid & 3) * 16;
        short8 w0 = *(const short8*)&T[dim * 72 + kc];
        short8 w1 = *(const short8*)&T[dim * 72 + kc + 8];
        short* dst = vt + ((size_t)bh * 64 + dim) * 2048 + nt + kc;
        *(short8*)dst = w0;
        *(short8*)(dst + 8) = w1;
    }
}

// ---------------------------------------------------------------------------
// GEMM with register-prefetch double buffering. C = A @ Bt^T (+bias).
// 128x128 tile, BK=32, 4 waves 2x2, each 64x64 via 4x4 MFMA.
// QSC: scale cols<1024 by log2(e)/32 (Q pre-scale for exp2 softmax).
// ---------------------------------------------------------------------------
template <typename TA, bool QSC, bool ADD_BIAS, typename TC>
__global__ __launch_bounds__(256) void gemm128(
    const TA* __restrict__ A, const short* __restrict__ Bt,
    const float* __restrict__ bias, TC* __restrict__ C,
    int M, int N, int K, int lda)
{
    __shared__ short A_s[128 * 40];
    __shared__ short B_s[128 * 40];
    const int tid  = threadIdx.x;
    const int lane = tid & 63;
    const int wave = tid >> 6;
    const int quad = lane >> 4;
    const int l16  = lane & 15;
    const int wr   = wave >> 1;
    const int wc   = wave & 1;
    const int bm   = blockIdx.y * 128;
    const int bn   = blockIdx.x * 128;

    f32x4 acc[4][4];
    #pragma unroll
    for (int i = 0; i < 4; ++i)
        #pragma unroll
        for (int j = 0; j < 4; ++j)
            acc[i][j] = f32x4{0.f, 0.f, 0.f, 0.f};

    const int s_row = tid >> 1;           // 0..127
    const int s_k   = (tid & 1) * 16;     // 0,16
    const TA*    ap = A  + (size_t)(bm + s_row) * lda + s_k;
    const short* bp = Bt + (size_t)(bn + s_row) * K   + s_k;

    short8 pa0 = ld8(ap), pa1 = ld8(ap + 8);
    short8 pb0 = *(const short8*)bp, pb1 = *(const short8*)(bp + 8);

    for (int k0 = 0; k0 < K; k0 += 32) {
        __syncthreads();
        *(short8*)&A_s[s_row * 40 + s_k]     = pa0;
        *(short8*)&A_s[s_row * 40 + s_k + 8] = pa1;
        *(short8*)&B_s[s_row * 40 + s_k]     = pb0;
        *(short8*)&B_s[s_row * 40 + s_k + 8] = pb1;
        if (k0 + 32 < K) {
            pa0 = ld8(ap + k0 + 32);
            pa1 = ld8(ap + k0 + 40);
            pb0 = *(const short8*)(bp + k0 + 32);
            pb1 = *(const short8*)(bp + k0 + 40);
        }
        __syncthreads();

        short8 a[4], b[4];
        #pragma unroll
        for (int i = 0; i < 4; ++i)
            a[i] = *(const short8*)&A_s[(wr * 64 + i * 16 + l16) * 40 + quad * 8];
        #pragma unroll
        for (int j = 0; j < 4; ++j)
            b[j] = *(const short8*)&B_s[(wc * 64 + j * 16 + l16) * 40 + quad * 8];
        #pragma unroll
        for (int i = 0; i < 4; ++i)
            #pragma unroll
            for (int j = 0; j < 4; ++j)
                acc[i][j] = mfma_bf16(a[i], b[j], acc[i][j]);
    }

    const float scale = (QSC && bn < 1024) ? QSCALE : 1.0f;
    #pragma unroll
    for (int i = 0; i < 4; ++i) {
        #pragma unroll
        for (int j = 0; j < 4; ++j) {
            #pragma unroll
            for (int r = 0; r < 4; ++r) {
                int row = bm + wr * 64 + i * 16 + quad * 4 + r;
                int col = bn + wc * 64 + j * 16 + l16;
                float v = acc[i][j][r] * scale;
                if (ADD_BIAS) v += bias[col];
                storeC(C, (size_t)row * N + col, v);
            }
        }
    }
}

// ---------------------------------------------------------------------------
// Flash attention v5: v4 (S^T MFMA -> exp2 -> direct PV via K=16 MFMA, no P
// LDS roundtrip) CHUNKED into 2 halves of 64 keys to keep the live register
// set ~100 VGPRs (v4 spilled: 150 live vs 128 cap -> 177MB scratch traffic).
// No min-waves bound: allocator takes what it needs; <=128 VGPR + 35KB LDS
// still gives 4 blocks/CU. ctx written in-place over q columns.
// grid (2048/64, 32) = 1024 blocks.
// ---------------------------------------------------------------------------
__global__ __launch_bounds__(256) void attn128(
    short* __restrict__ qkv, const short* __restrict__ vt)
{
    __shared__ short Ks[128 * 72];   // [key][dim]
    __shared__ short Vs[16 * 520];   // [g][dim][k&7], g = key>>3 (tile-local)

    const int tid  = threadIdx.x;
    const int lane = tid & 63;
    const int wave = tid >> 6;
    const int quad = lane >> 4;
    const int l16  = lane & 15;
    const int bh   = blockIdx.y, b = bh >> 4, h = bh & 15;
    const int qb   = blockIdx.x * 64;
    const size_t rowbase = (size_t)b * 2048;

    // Q fragments (B-op for S^T: n=l16, k=quad*8+j), pre-scaled by log2e/32
    short8 aq0, aq1;
    {
        const short* qp = qkv + (rowbase + qb + wave * 16 + l16) * 3072 + h * 64;
        aq0 = *(const short8*)(qp + quad * 8);
        aq1 = *(const short8*)(qp + 32 + quad * 8);
    }

    f32x4 o[4];
    #pragma unroll
    for (int c = 0; c < 4; ++c) o[c] = f32x4{0.f, 0.f, 0.f, 0.f};
    float rsum = 0.f;   // softmax denom partial for q = l16

    const int kkey = tid >> 1, kdc = (tid & 1) * 32;
    const int vdim = tid >> 2, vg0 = (tid & 3) * 4;    // 4 key-groups per lane
    const short* kbase = qkv + (rowbase + kkey) * 3072 + 1024 + h * 64 + kdc;
    const short* vbase = vt + ((size_t)bh * 64 + vdim) * 2048 + vg0 * 8;

    // prefetch tile 0
    short8 kr0 = *(const short8*)(kbase);
    short8 kr1 = *(const short8*)(kbase + 8);
    short8 kr2 = *(const short8*)(kbase + 16);
    short8 kr3 = *(const short8*)(kbase + 24);
    short8 vr0 = *(const short8*)(vbase);
    short8 vr1 = *(const short8*)(vbase + 8);
    short8 vr2 = *(const short8*)(vbase + 16);
    short8 vr3 = *(const short8*)(vbase + 24);

    for (int kt = 0; kt < 2048; kt += 128) {
        __syncthreads();                      // prior-tile LDS readers done
        *(short8*)&Ks[kkey * 72 + kdc]      = kr0;
        *(short8*)&Ks[kkey * 72 + kdc + 8]  = kr1;
        *(short8*)&Ks[kkey * 72 + kdc + 16] = kr2;
        *(short8*)&Ks[kkey * 72 + kdc + 24] = kr3;
        *(short8*)&Vs[(vg0 + 0) * 520 + vdim * 8] = vr0;
        *(short8*)&Vs[(vg0 + 1) * 520 + vdim * 8] = vr1;
        *(short8*)&Vs[(vg0 + 2) * 520 + vdim * 8] = vr2;
        *(short8*)&Vs[(vg0 + 3) * 520 + vdim * 8] = vr3;
        if (kt + 128 < 2048) {                // prefetch next tile
            const short* kp = kbase + (size_t)(kt + 128) * 3072;
            kr0 = *(const short8*)(kp);
            kr1 = *(const short8*)(kp + 8);
            kr2 = *(const short8*)(kp + 16);
            kr3 = *(const short8*)(kp + 24);
            const short* vp = vbase + kt + 128;
            vr0 = *(const short8*)(vp);
            vr1 = *(const short8*)(vp + 8);
            vr2 = *(const short8*)(vp + 16);
            vr3 = *(const short8*)(vp + 24);
        }
        __syncthreads();                      // tile visible

        // two chunks of 64 keys: S^T -> exp2 -> PV, short live ranges
        #pragma unroll
        for (int cc = 0; cc < 2; ++cc) {
            // S^T: lane holds S[q=l16][key = (cc*4+c4)*16 + quad*4 + r]
            f32x4 st[4];
            #pragma unroll
            for (int c4 = 0; c4 < 4; ++c4) {
                const int c = cc * 4 + c4;
                short8 ka0 = *(const short8*)&Ks[(c * 16 + l16) * 72 + quad * 8];
                short8 ka1 = *(const short8*)&Ks[(c * 16 + l16) * 72 + 32 + quad * 8];
                f32x4 z = f32x4{0.f, 0.f, 0.f, 0.f};
                z = mfma_bf16(ka0, aq0, z);
                st[c4] = mfma_bf16(ka1, aq1, z);
            }
            // p = exp2(s'); pack straight into PV A-fragments (K=16 layout)
            uint2v pa[4];
            #pragma unroll
            for (int c4 = 0; c4 < 4; ++c4) {
                float p0 = exp2f(st[c4][0]);
                float p1 = exp2f(st[c4][1]);
                float p2 = exp2f(st[c4][2]);
                float p3 = exp2f(st[c4][3]);
                rsum += (p0 + p1) + (p2 + p3);
                uint2v pk;
                pk[0] = pkbf(p0, p1);
                pk[1] = pkbf(p2, p3);
                pa[c4] = pk;
            }
            // PV: O[q][dim] += P[q][key] V[key][dim], K=16 per MFMA
            #pragma unroll
            for (int c2 = 0; c2 < 4; ++c2) {
                #pragma unroll
                for (int c4 = 0; c4 < 4; ++c4) {
                    const int c = cc * 4 + c4;
                    uint2v bv = *(const uint2v*)&Vs[(2 * c + (quad >> 1)) * 520
                                                    + (c2 * 16 + l16) * 8
                                                    + (quad & 1) * 4];
                    o[c2] = mfma16(pa[c4], bv, o[c2]);
                }
            }
        }
    }

    // full denom for q=l16: sum over the 4 quad-lanes
    rsum += __shfl_xor(rsum, 16, 64);
    rsum += __shfl_xor(rsum, 32, 64);

    // epilogue: o rows are q=quad*4+r; fetch that q's denom from lane q
    #pragma unroll
    for (int r = 0; r < 4; ++r) {
        float inv = 1.0f / __shfl(rsum, quad * 4 + r, 64);
        size_t row = rowbase + qb + wave * 16 + quad * 4 + r;
        #pragma unroll
        for (int c2 = 0; c2 < 4; ++c2)
            qkv[row * 3072 + h * 64 + c2 * 16 + l16] = f2b(o[c2][r] * inv);
    }
}

// ---------------------------------------------------------------------------
extern "C" void kernel_launch(void* const* d_in, const int* in_sizes, int n_in,
                              void* d_out, int out_size, void* d_ws, size_t ws_size,
                              hipStream_t stream)
{
    const float* x    = (const float*)d_in[0];   // (2,2048,1024) fp32
    const float* Wqkv = (const float*)d_in[2];   // (1024,3072) fp32
    const float* Wout = (const float*)d_in[3];   // (1024,1024) fp32
    const float* bout = (const float*)d_in[4];   // (1024,) fp32
    float* out = (float*)d_out;                  // (2,2048,1024) fp32

    // ws: 32 MiB. qkv 24 MiB | 8 MiB region time-shared: Wqkvt -> vt -> Woutt
    short* qkv    = (short*)d_ws;                // 4096 x 3072 bf16
    short* vtbuf  = qkv + (size_t)4096 * 3072;   // 8 MiB region
    short* wqkvt  = vtbuf;                       // 3072 x 1024 bf16
    short* woutt  = vtbuf;                       // 1024 x 1024 bf16

    dim3 blk(256);
    transpose_w<<<dim3(48, 16), blk, 0, stream>>>(Wqkv, wqkvt, 1024, 3072);
    gemm128<float, true, false, short><<<dim3(24, 32), blk, 0, stream>>>(
        x, wqkvt, nullptr, qkv, 4096, 3072, 1024, 1024);
    vtrans<<<dim3(32, 32), blk, 0, stream>>>(qkv, vtbuf);
    attn128<<<dim3(32, 32), blk, 0, stream>>>(qkv, vtbuf);
    transpose_w<<<dim3(16, 16), blk, 0, stream>>>(Wout, woutt, 1024, 1024);
    gemm128<short, false, true, float><<<dim3(8, 32), blk, 0, stream>>>(
        qkv, woutt, bout, out, 4096, 1024, 1024, 3072);
}

// Round 9
// 221.982 us; speedup vs baseline: 1.2014x; 1.0787x over previous
//
#include <hip/hip_runtime.h>

typedef __attribute__((ext_vector_type(8))) short short8;
typedef __attribute__((ext_vector_type(4))) short s16x4;
typedef __attribute__((ext_vector_type(8))) __bf16 bf16x8;
typedef __attribute__((ext_vector_type(4))) __bf16 bf16x4;
typedef __attribute__((ext_vector_type(4))) float f32x4;
typedef __attribute__((ext_vector_type(4))) unsigned uint4v;
typedef __attribute__((ext_vector_type(2))) unsigned uint2v;

__device__ inline f32x4 mfma_bf16(short8 a, short8 b, f32x4 c) {
    return __builtin_amdgcn_mfma_f32_16x16x32_bf16(
        __builtin_bit_cast(bf16x8, a), __builtin_bit_cast(bf16x8, b), c, 0, 0, 0);
}
// K=16 bf16 MFMA: A-frag layout A[m=l16][k=quad*4+j] == C/D layout of a prior
// MFMA transposed -> P needs no layout transform.
__device__ inline f32x4 mfma16(uint2v a, uint2v b, f32x4 c) {
#if __has_builtin(__builtin_amdgcn_mfma_f32_16x16x16_bf16)
    return __builtin_amdgcn_mfma_f32_16x16x16_bf16(
        __builtin_bit_cast(bf16x4, a), __builtin_bit_cast(bf16x4, b), c, 0, 0, 0);
#else
    return __builtin_amdgcn_mfma_f32_16x16x16bf16_1k(
        __builtin_bit_cast(s16x4, a), __builtin_bit_cast(s16x4, b), c, 0, 0, 0);
#endif
}

// round-to-nearest-even fp32 -> bf16 bits
__device__ inline unsigned f2b_u(float f) {
    unsigned u = __float_as_uint(f);
    return (u + 0x7fffu + ((u >> 16) & 1u)) >> 16;
}
__device__ inline short f2b(float f) { return (short)f2b_u(f); }
__device__ inline unsigned pkbf(float a, float b) {
    return f2b_u(a) | (f2b_u(b) << 16);
}

__device__ inline short8 ld8(const short* p) { return *(const short8*)p; }
__device__ inline short8 ld8(const float* p) {
    f32x4 a = *(const f32x4*)p;
    f32x4 b = *(const f32x4*)(p + 4);
    uint4v q;
    q[0] = pkbf(a[0], a[1]); q[1] = pkbf(a[2], a[3]);
    q[2] = pkbf(b[0], b[1]); q[3] = pkbf(b[2], b[3]);
    return __builtin_bit_cast(short8, q);
}
__device__ inline void storeC(short* C, size_t i, float v) { C[i] = f2b(v); }
__device__ inline void storeC(float* C, size_t i, float v) { C[i] = v; }

// log2(e)/32 : folded into Q so softmax uses exp2 (bare v_exp_f32)
#define QSCALE 0.04508422052265167f

// ---------------------------------------------------------------------------
// fp32 -> bf16 bulk convert (x -> xbf in d_out scratch). n multiple of 2048.
// ---------------------------------------------------------------------------
__global__ __launch_bounds__(256) void cvt_bf16(
    const float* __restrict__ x, short* __restrict__ xb)
{
    size_t i = ((size_t)blockIdx.x * 256 + threadIdx.x) * 8;
    *(short8*)(xb + i) = ld8(x + i);
}

// ---------------------------------------------------------------------------
// W [K][N] fp32 row-major -> Wt [N][K] bf16 k-major. grid (N/64, K/64).
// ---------------------------------------------------------------------------
__global__ __launch_bounds__(256) void transpose_w(
    const float* __restrict__ W, short* __restrict__ Wt, int K, int N)
{
    __shared__ short T[64 * 72];
    const int tid = threadIdx.x;
    const int n0 = blockIdx.x * 64, k0 = blockIdx.y * 64;
    {
        const int kl = tid >> 2, nc = (tid & 3) * 16;
        const float* src = W + (size_t)(k0 + kl) * N + n0 + nc;
        float v[16];
        *(f32x4*)&v[0]  = *(const f32x4*)(src + 0);
        *(f32x4*)&v[4]  = *(const f32x4*)(src + 4);
        *(f32x4*)&v[8]  = *(const f32x4*)(src + 8);
        *(f32x4*)&v[12] = *(const f32x4*)(src + 12);
        #pragma unroll
        for (int j = 0; j < 16; ++j) T[(nc + j) * 72 + kl] = f2b(v[j]);
    }
    __syncthreads();
    {
        const int nl = tid >> 2, kc = (tid & 3) * 16;
        short8 w0 = *(const short8*)&T[nl * 72 + kc];
        short8 w1 = *(const short8*)&T[nl * 72 + kc + 8];
        short* dst = Wt + (size_t)(n0 + nl) * K + k0 + kc;
        *(short8*)dst = w0;
        *(short8*)(dst + 8) = w1;
    }
}

// ---------------------------------------------------------------------------
// V transpose: qkv (B*N,3072) bf16 cols 2048+h*64 -> vt[(b*16+h)][dim][2048].
// ---------------------------------------------------------------------------
__global__ __launch_bounds__(256) void vtrans(
    const short* __restrict__ qkv, short* __restrict__ vt)
{
    __shared__ short T[64 * 72];
    const int tid = threadIdx.x;
    const int nt = blockIdx.x * 64, bh = blockIdx.y;
    const int b = bh >> 4, h = bh & 15;
    {
        const int tok = tid >> 2, dc = (tid & 3) * 16;
        const short* src = qkv + ((size_t)b * 2048 + nt + tok) * 3072 + 2048 + h * 64 + dc;
        short8 v0 = *(const short8*)src;
        short8 v1 = *(const short8*)(src + 8);
        #pragma unroll
        for (int j = 0; j < 8; ++j) {
            T[(dc + j) * 72 + tok]     = v0[j];
            T[(dc + 8 + j) * 72 + tok] = v1[j];
        }
    }
    __syncthreads();
    {
        const int dim = tid >> 2, kc = (tid & 3) * 16;
        short8 w0 = *(const short8*)&T[dim * 72 + kc];
        short8 w1 = *(const short8*)&T[dim * 72 + kc + 8];
        short* dst = vt + ((size_t)bh * 64 + dim) * 2048 + nt + kc;
        *(short8*)dst = w0;
        *(short8*)(dst + 8) = w1;
    }
}

// ---------------------------------------------------------------------------
// GEMM with register-prefetch double buffering. C = A @ Bt^T (+bias).
// A bf16 (lda), Bt bf16 k-major. 128x128 tile, BK=32, 4 waves 2x2.
// QSC: scale cols<1024 by log2(e)/32 (Q pre-scale for exp2 softmax).
// ---------------------------------------------------------------------------
template <bool QSC, bool ADD_BIAS, typename TC>
__global__ __launch_bounds__(256) void gemm128(
    const short* __restrict__ A, const short* __restrict__ Bt,
    const float* __restrict__ bias, TC* __restrict__ C,
    int M, int N, int K, int lda)
{
    __shared__ short A_s[128 * 40];
    __shared__ short B_s[128 * 40];
    const int tid  = threadIdx.x;
    const int lane = tid & 63;
    const int wave = tid >> 6;
    const int quad = lane >> 4;
    const int l16  = lane & 15;
    const int wr   = wave >> 1;
    const int wc   = wave & 1;
    const int bm   = blockIdx.y * 128;
    const int bn   = blockIdx.x * 128;

    f32x4 acc[4][4];
    #pragma unroll
    for (int i = 0; i < 4; ++i)
        #pragma unroll
        for (int j = 0; j < 4; ++j)
            acc[i][j] = f32x4{0.f, 0.f, 0.f, 0.f};

    const int s_row = tid >> 1;           // 0..127
    const int s_k   = (tid & 1) * 16;     // 0,16
    const short* ap = A  + (size_t)(bm + s_row) * lda + s_k;
    const short* bp = Bt + (size_t)(bn + s_row) * K   + s_k;

    short8 pa0 = *(const short8*)ap, pa1 = *(const short8*)(ap + 8);
    short8 pb0 = *(const short8*)bp, pb1 = *(const short8*)(bp + 8);

    for (int k0 = 0; k0 < K; k0 += 32) {
        __syncthreads();
        *(short8*)&A_s[s_row * 40 + s_k]     = pa0;
        *(short8*)&A_s[s_row * 40 + s_k + 8] = pa1;
        *(short8*)&B_s[s_row * 40 + s_k]     = pb0;
        *(short8*)&B_s[s_row * 40 + s_k + 8] = pb1;
        if (k0 + 32 < K) {
            pa0 = *(const short8*)(ap + k0 + 32);
            pa1 = *(const short8*)(ap + k0 + 40);
            pb0 = *(const short8*)(bp + k0 + 32);
            pb1 = *(const short8*)(bp + k0 + 40);
        }
        __syncthreads();

        short8 a[4], b[4];
        #pragma unroll
        for (int i = 0; i < 4; ++i)
            a[i] = *(const short8*)&A_s[(wr * 64 + i * 16 + l16) * 40 + quad * 8];
        #pragma unroll
        for (int j = 0; j < 4; ++j)
            b[j] = *(const short8*)&B_s[(wc * 64 + j * 16 + l16) * 40 + quad * 8];
        #pragma unroll
        for (int i = 0; i < 4; ++i)
            #pragma unroll
            for (int j = 0; j < 4; ++j)
                acc[i][j] = mfma_bf16(a[i], b[j], acc[i][j]);
    }

    const float scale = (QSC && bn < 1024) ? QSCALE : 1.0f;
    #pragma unroll
    for (int i = 0; i < 4; ++i) {
        #pragma unroll
        for (int j = 0; j < 4; ++j) {
            #pragma unroll
            for (int r = 0; r < 4; ++r) {
                int row = bm + wr * 64 + i * 16 + quad * 4 + r;
                int col = bn + wc * 64 + j * 16 + l16;
                float v = acc[i][j][r] * scale;
                if (ADD_BIAS) v += bias[col];
                storeC(C, (size_t)row * N + col, v);
            }
        }
    }
}

// ---------------------------------------------------------------------------
// Flash attention v6: 32 q-rows per wave (Q-block 128). The q-independent
// LDS fragment reads (K for S^T, V for PV) are read ONCE and reused for both
// q-groups -> LDS-pipe cycles per unit work halve (it was the round-8
// bottleneck: ~58 of 95 us). 2 blocks/CU -> 256 VGPR/wave budget, no spills.
// S^T MFMA -> exp2 -> direct K=16 PV (no P roundtrip), ctx in-place over q.
// grid (2048/128, 32) = 512 blocks.
// ---------------------------------------------------------------------------
__global__ __launch_bounds__(256) void attn128(
    short* __restrict__ qkv, const short* __restrict__ vt)
{
    __shared__ short Ks[128 * 72];   // [key][dim]
    __shared__ short Vs[16 * 520];   // [g][dim][k&7], g = key>>3 (tile-local)

    const int tid  = threadIdx.x;
    const int lane = tid & 63;
    const int wave = tid >> 6;
    const int quad = lane >> 4;
    const int l16  = lane & 15;
    const int bh   = blockIdx.y, b = bh >> 4, h = bh & 15;
    const int qb   = blockIdx.x * 128;
    const size_t rowbase = (size_t)b * 2048;

    // Q fragments for 2 q-groups (B-op for S^T), pre-scaled by log2e/32
    short8 aq[2][2];
    #pragma unroll
    for (int qg = 0; qg < 2; ++qg) {
        const short* qp = qkv + (rowbase + qb + wave * 32 + qg * 16 + l16) * 3072 + h * 64;
        aq[qg][0] = *(const short8*)(qp + quad * 8);
        aq[qg][1] = *(const short8*)(qp + 32 + quad * 8);
    }

    f32x4 o[2][4];
    #pragma unroll
    for (int qg = 0; qg < 2; ++qg)
        #pragma unroll
        for (int c = 0; c < 4; ++c) o[qg][c] = f32x4{0.f, 0.f, 0.f, 0.f};
    float rsum[2] = {0.f, 0.f};   // softmax denom partials for q = l16

    const int kkey = tid >> 1, kdc = (tid & 1) * 32;
    const int vdim = tid >> 2, vg0 = (tid & 3) * 4;
    const short* kbase = qkv + (rowbase + kkey) * 3072 + 1024 + h * 64 + kdc;
    const short* vbase = vt + ((size_t)bh * 64 + vdim) * 2048 + vg0 * 8;

    // prefetch tile 0
    short8 kr0 = *(const short8*)(kbase);
    short8 kr1 = *(const short8*)(kbase + 8);
    short8 kr2 = *(const short8*)(kbase + 16);
    short8 kr3 = *(const short8*)(kbase + 24);
    short8 vr0 = *(const short8*)(vbase);
    short8 vr1 = *(const short8*)(vbase + 8);
    short8 vr2 = *(const short8*)(vbase + 16);
    short8 vr3 = *(const short8*)(vbase + 24);

    for (int kt = 0; kt < 2048; kt += 128) {
        __syncthreads();                      // prior-tile LDS readers done
        *(short8*)&Ks[kkey * 72 + kdc]      = kr0;
        *(short8*)&Ks[kkey * 72 + kdc + 8]  = kr1;
        *(short8*)&Ks[kkey * 72 + kdc + 16] = kr2;
        *(short8*)&Ks[kkey * 72 + kdc + 24] = kr3;
        *(short8*)&Vs[(vg0 + 0) * 520 + vdim * 8] = vr0;
        *(short8*)&Vs[(vg0 + 1) * 520 + vdim * 8] = vr1;
        *(short8*)&Vs[(vg0 + 2) * 520 + vdim * 8] = vr2;
        *(short8*)&Vs[(vg0 + 3) * 520 + vdim * 8] = vr3;
        if (kt + 128 < 2048) {                // prefetch next tile
            const short* kp = kbase + (size_t)(kt + 128) * 3072;
            kr0 = *(const short8*)(kp);
            kr1 = *(const short8*)(kp + 8);
            kr2 = *(const short8*)(kp + 16);
            kr3 = *(const short8*)(kp + 24);
            const short* vp = vbase + kt + 128;
            vr0 = *(const short8*)(vp);
            vr1 = *(const short8*)(vp + 8);
            vr2 = *(const short8*)(vp + 16);
            vr3 = *(const short8*)(vp + 24);
        }
        __syncthreads();                      // tile visible

        // two chunks of 64 keys: S^T -> exp2 -> PV
        #pragma unroll
        for (int cc = 0; cc < 2; ++cc) {
            // S^T: lane holds S[q=l16][key=(cc*4+c4)*16+quad*4+r], per q-group
            f32x4 st[2][4];
            #pragma unroll
            for (int c4 = 0; c4 < 4; ++c4) {
                const int c = cc * 4 + c4;
                short8 ka0 = *(const short8*)&Ks[(c * 16 + l16) * 72 + quad * 8];
                short8 ka1 = *(const short8*)&Ks[(c * 16 + l16) * 72 + 32 + quad * 8];
                #pragma unroll
                for (int qg = 0; qg < 2; ++qg) {
                    f32x4 z = f32x4{0.f, 0.f, 0.f, 0.f};
                    z = mfma_bf16(ka0, aq[qg][0], z);
                    st[qg][c4] = mfma_bf16(ka1, aq[qg][1], z);
                }
            }
            // p = exp2(s'); pack straight into PV A-fragments (K=16 layout)
            uint2v pa[2][4];
            #pragma unroll
            for (int qg = 0; qg < 2; ++qg) {
                #pragma unroll
                for (int c4 = 0; c4 < 4; ++c4) {
                    float p0 = exp2f(st[qg][c4][0]);
                    float p1 = exp2f(st[qg][c4][1]);
                    float p2 = exp2f(st[qg][c4][2]);
                    float p3 = exp2f(st[qg][c4][3]);
                    rsum[qg] += (p0 + p1) + (p2 + p3);
                    uint2v pk;
                    pk[0] = pkbf(p0, p1);
                    pk[1] = pkbf(p2, p3);
                    pa[qg][c4] = pk;
                }
            }
            // PV: bv read once, used by both q-groups
            #pragma unroll
            for (int c2 = 0; c2 < 4; ++c2) {
                #pragma unroll
                for (int c4 = 0; c4 < 4; ++c4) {
                    const int c = cc * 4 + c4;
                    uint2v bv = *(const uint2v*)&Vs[(2 * c + (quad >> 1)) * 520
                                                    + (c2 * 16 + l16) * 8
                                                    + (quad & 1) * 4];
                    #pragma unroll
                    for (int qg = 0; qg < 2; ++qg)
                        o[qg][c2] = mfma16(pa[qg][c4], bv, o[qg][c2]);
                }
            }
        }
    }

    // full denom for q=l16: sum over the 4 quad-lanes
    #pragma unroll
    for (int qg = 0; qg < 2; ++qg) {
        rsum[qg] += __shfl_xor(rsum[qg], 16, 64);
        rsum[qg] += __shfl_xor(rsum[qg], 32, 64);
    }

    // epilogue: o rows are q=quad*4+r; fetch that q's denom from lane q
    #pragma unroll
    for (int qg = 0; qg < 2; ++qg) {
        #pragma unroll
        for (int r = 0; r < 4; ++r) {
            float inv = 1.0f / __shfl(rsum[qg], quad * 4 + r, 64);
            size_t row = rowbase + qb + wave * 32 + qg * 16 + quad * 4 + r;
            #pragma unroll
            for (int c2 = 0; c2 < 4; ++c2)
                qkv[row * 3072 + h * 64 + c2 * 16 + l16] = f2b(o[qg][c2][r] * inv);
        }
    }
}

// ---------------------------------------------------------------------------
extern "C" void kernel_launch(void* const* d_in, const int* in_sizes, int n_in,
                              void* d_out, int out_size, void* d_ws, size_t ws_size,
                              hipStream_t stream)
{
    const float* x    = (const float*)d_in[0];   // (2,2048,1024) fp32
    const float* Wqkv = (const float*)d_in[2];   // (1024,3072) fp32
    const float* Wout = (const float*)d_in[3];   // (1024,1024) fp32
    const float* bout = (const float*)d_in[4];   // (1024,) fp32
    float* out = (float*)d_out;                  // (2,2048,1024) fp32

    // ws: 32 MiB. qkv 24 MiB | 8 MiB region time-shared: Wqkvt -> vt -> Woutt
    // d_out doubles as scratch for xbf (first 8 MiB) until gemm2 overwrites.
    short* qkv    = (short*)d_ws;                // 4096 x 3072 bf16
    short* vtbuf  = qkv + (size_t)4096 * 3072;   // 8 MiB region
    short* wqkvt  = vtbuf;                       // 3072 x 1024 bf16
    short* woutt  = vtbuf;                       // 1024 x 1024 bf16
    short* xbf    = (short*)d_out;               // 4096 x 1024 bf16 (scratch)

    dim3 blk(256);
    cvt_bf16<<<dim3(2048), blk, 0, stream>>>(x, xbf);
    transpose_w<<<dim3(48, 16), blk, 0, stream>>>(Wqkv, wqkvt, 1024, 3072);
    gemm128<true, false, short><<<dim3(24, 32), blk, 0, stream>>>(
        xbf, wqkvt, nullptr, qkv, 4096, 3072, 1024, 1024);
    vtrans<<<dim3(32, 32), blk, 0, stream>>>(qkv, vtbuf);
    attn128<<<dim3(16, 32), blk, 0, stream>>>(qkv, vtbuf);
    transpose_w<<<dim3(16, 16), blk, 0, stream>>>(Wout, woutt, 1024, 1024);
    gemm128<false, true, float><<<dim3(8, 32), blk, 0, stream>>>(
        qkv, woutt, bout, out, 4096, 1024, 1024, 3072);
}

// Round 10
// 197.157 us; speedup vs baseline: 1.3527x; 1.1259x over previous
//
#include <hip/hip_runtime.h>

typedef __attribute__((ext_vector_type(8))) short short8;
typedef __attribute__((ext_vector_type(4))) short s16x4;
typedef __attribute__((ext_vector_type(8))) __bf16 bf16x8;
typedef __attribute__((ext_vector_type(4))) __bf16 bf16x4;
typedef __attribute__((ext_vector_type(2))) __bf16 bf16x2;
typedef __attribute__((ext_vector_type(4))) float f32x4;
typedef __attribute__((ext_vector_type(2))) float f32x2;
typedef __attribute__((ext_vector_type(4))) unsigned uint4v;
typedef __attribute__((ext_vector_type(2))) unsigned uint2v;

__device__ inline f32x4 mfma_bf16(short8 a, short8 b, f32x4 c) {
    return __builtin_amdgcn_mfma_f32_16x16x32_bf16(
        __builtin_bit_cast(bf16x8, a), __builtin_bit_cast(bf16x8, b), c, 0, 0, 0);
}
// K=16 bf16 MFMA: A-frag layout A[m=l16][k=quad*4+j] == C/D layout of a prior
// MFMA transposed -> P needs no layout transform.
__device__ inline f32x4 mfma16(uint2v a, uint2v b, f32x4 c) {
#if __has_builtin(__builtin_amdgcn_mfma_f32_16x16x16_bf16)
    return __builtin_amdgcn_mfma_f32_16x16x16_bf16(
        __builtin_bit_cast(bf16x4, a), __builtin_bit_cast(bf16x4, b), c, 0, 0, 0);
#else
    return __builtin_amdgcn_mfma_f32_16x16x16bf16_1k(
        __builtin_bit_cast(s16x4, a), __builtin_bit_cast(s16x4, b), c, 0, 0, 0);
#endif
}

// fast exp2: bare v_exp_f32
__device__ inline float fexp2(float x) {
#if __has_builtin(__builtin_amdgcn_exp2f)
    return __builtin_amdgcn_exp2f(x);
#else
    return exp2f(x);
#endif
}

// fp32 -> bf16 via HW convert (v_cvt_pk_bf16_f32 on gfx950), RNE
__device__ inline short f2b(float f) {
    __bf16 h = (__bf16)f;
    return __builtin_bit_cast(short, h);
}
__device__ inline unsigned pkbf(float a, float b) {
    f32x2 v; v[0] = a; v[1] = b;
    bf16x2 h = __builtin_convertvector(v, bf16x2);
    return __builtin_bit_cast(unsigned, h);
}

__device__ inline short8 ld8(const short* p) { return *(const short8*)p; }
__device__ inline short8 ld8(const float* p) {
    f32x4 a = *(const f32x4*)p;
    f32x4 b = *(const f32x4*)(p + 4);
    uint4v q;
    q[0] = pkbf(a[0], a[1]); q[1] = pkbf(a[2], a[3]);
    q[2] = pkbf(b[0], b[1]); q[3] = pkbf(b[2], b[3]);
    return __builtin_bit_cast(short8, q);
}
__device__ inline void storeC(short* C, size_t i, float v) { C[i] = f2b(v); }
__device__ inline void storeC(float* C, size_t i, float v) { C[i] = v; }

// log2(e)/32 : folded into Q so softmax uses exp2 (bare v_exp_f32)
#define QSCALE 0.04508422052265167f

// ---------------------------------------------------------------------------
// fp32 -> bf16 bulk convert (x -> xbf in d_out scratch). n multiple of 2048.
// ---------------------------------------------------------------------------
__global__ __launch_bounds__(256) void cvt_bf16(
    const float* __restrict__ x, short* __restrict__ xb)
{
    size_t i = ((size_t)blockIdx.x * 256 + threadIdx.x) * 8;
    *(short8*)(xb + i) = ld8(x + i);
}

// ---------------------------------------------------------------------------
// W [K][N] fp32 row-major -> Wt [N][K] bf16 k-major. grid (N/64, K/64).
// ---------------------------------------------------------------------------
__global__ __launch_bounds__(256) void transpose_w(
    const float* __restrict__ W, short* __restrict__ Wt, int K, int N)
{
    __shared__ short T[64 * 72];
    const int tid = threadIdx.x;
    const int n0 = blockIdx.x * 64, k0 = blockIdx.y * 64;
    {
        const int kl = tid >> 2, nc = (tid & 3) * 16;
        const float* src = W + (size_t)(k0 + kl) * N + n0 + nc;
        float v[16];
        *(f32x4*)&v[0]  = *(const f32x4*)(src + 0);
        *(f32x4*)&v[4]  = *(const f32x4*)(src + 4);
        *(f32x4*)&v[8]  = *(const f32x4*)(src + 8);
        *(f32x4*)&v[12] = *(const f32x4*)(src + 12);
        #pragma unroll
        for (int j = 0; j < 16; ++j) T[(nc + j) * 72 + kl] = f2b(v[j]);
    }
    __syncthreads();
    {
        const int nl = tid >> 2, kc = (tid & 3) * 16;
        short8 w0 = *(const short8*)&T[nl * 72 + kc];
        short8 w1 = *(const short8*)&T[nl * 72 + kc + 8];
        short* dst = Wt + (size_t)(n0 + nl) * K + k0 + kc;
        *(short8*)dst = w0;
        *(short8*)(dst + 8) = w1;
    }
}

// ---------------------------------------------------------------------------
// V transpose: qkv (B*N,3072) bf16 cols 2048+h*64 -> vt[(b*16+h)][dim][2048].
// ---------------------------------------------------------------------------
__global__ __launch_bounds__(256) void vtrans(
    const short* __restrict__ qkv, short* __restrict__ vt)
{
    __shared__ short T[64 * 72];
    const int tid = threadIdx.x;
    const int nt = blockIdx.x * 64, bh = blockIdx.y;
    const int b = bh >> 4, h = bh & 15;
    {
        const int tok = tid >> 2, dc = (tid & 3) * 16;
        const short* src = qkv + ((size_t)b * 2048 + nt + tok) * 3072 + 2048 + h * 64 + dc;
        short8 v0 = *(const short8*)src;
        short8 v1 = *(const short8*)(src + 8);
        #pragma unroll
        for (int j = 0; j < 8; ++j) {
            T[(dc + j) * 72 + tok]     = v0[j];
            T[(dc + 8 + j) * 72 + tok] = v1[j];
        }
    }
    __syncthreads();
    {
        const int dim = tid >> 2, kc = (tid & 3) * 16;
        short8 w0 = *(const short8*)&T[dim * 72 + kc];
        short8 w1 = *(const short8*)&T[dim * 72 + kc + 8];
        short* dst = vt + ((size_t)bh * 64 + dim) * 2048 + nt + kc;
        *(short8*)dst = w0;
        *(short8*)(dst + 8) = w1;
    }
}

// ---------------------------------------------------------------------------
// GEMM with register-prefetch double buffering. C = A @ Bt^T (+bias).
// A bf16 (lda), Bt bf16 k-major. 128x128 tile, BK=32, 4 waves 2x2.
// QSC: scale cols<1024 by log2(e)/32 (Q pre-scale for exp2 softmax).
// ---------------------------------------------------------------------------
template <bool QSC, bool ADD_BIAS, typename TC>
__global__ __launch_bounds__(256) void gemm128(
    const short* __restrict__ A, const short* __restrict__ Bt,
    const float* __restrict__ bias, TC* __restrict__ C,
    int M, int N, int K, int lda)
{
    __shared__ short A_s[128 * 40];
    __shared__ short B_s[128 * 40];
    const int tid  = threadIdx.x;
    const int lane = tid & 63;
    const int wave = tid >> 6;
    const int quad = lane >> 4;
    const int l16  = lane & 15;
    const int wr   = wave >> 1;
    const int wc   = wave & 1;
    const int bm   = blockIdx.y * 128;
    const int bn   = blockIdx.x * 128;

    f32x4 acc[4][4];
    #pragma unroll
    for (int i = 0; i < 4; ++i)
        #pragma unroll
        for (int j = 0; j < 4; ++j)
            acc[i][j] = f32x4{0.f, 0.f, 0.f, 0.f};

    const int s_row = tid >> 1;           // 0..127
    const int s_k   = (tid & 1) * 16;     // 0,16
    const short* ap = A  + (size_t)(bm + s_row) * lda + s_k;
    const short* bp = Bt + (size_t)(bn + s_row) * K   + s_k;

    short8 pa0 = *(const short8*)ap, pa1 = *(const short8*)(ap + 8);
    short8 pb0 = *(const short8*)bp, pb1 = *(const short8*)(bp + 8);

    for (int k0 = 0; k0 < K; k0 += 32) {
        __syncthreads();
        *(short8*)&A_s[s_row * 40 + s_k]     = pa0;
        *(short8*)&A_s[s_row * 40 + s_k + 8] = pa1;
        *(short8*)&B_s[s_row * 40 + s_k]     = pb0;
        *(short8*)&B_s[s_row * 40 + s_k + 8] = pb1;
        if (k0 + 32 < K) {
            pa0 = *(const short8*)(ap + k0 + 32);
            pa1 = *(const short8*)(ap + k0 + 40);
            pb0 = *(const short8*)(bp + k0 + 32);
            pb1 = *(const short8*)(bp + k0 + 40);
        }
        __syncthreads();

        short8 a[4], b[4];
        #pragma unroll
        for (int i = 0; i < 4; ++i)
            a[i] = *(const short8*)&A_s[(wr * 64 + i * 16 + l16) * 40 + quad * 8];
        #pragma unroll
        for (int j = 0; j < 4; ++j)
            b[j] = *(const short8*)&B_s[(wc * 64 + j * 16 + l16) * 40 + quad * 8];
        #pragma unroll
        for (int i = 0; i < 4; ++i)
            #pragma unroll
            for (int j = 0; j < 4; ++j)
                acc[i][j] = mfma_bf16(a[i], b[j], acc[i][j]);
    }

    const float scale = (QSC && bn < 1024) ? QSCALE : 1.0f;
    #pragma unroll
    for (int i = 0; i < 4; ++i) {
        #pragma unroll
        for (int j = 0; j < 4; ++j) {
            #pragma unroll
            for (int r = 0; r < 4; ++r) {
                int row = bm + wr * 64 + i * 16 + quad * 4 + r;
                int col = bn + wc * 64 + j * 16 + l16;
                float v = acc[i][j][r] * scale;
                if (ADD_BIAS) v += bias[col];
                storeC(C, (size_t)row * N + col, v);
            }
        }
    }
}

// ---------------------------------------------------------------------------
// Flash attention v7 = v6 structure + HW softmax conversion: exp2 via bare
// v_exp_f32 and P-packing via v_cvt_pk_bf16_f32 (was ~850 VALU insts per
// lane-tile of libcall exp2f + manual RNE packing -> ~150). 32 q-rows per
// wave, q-independent K/V fragment reads amortized across both q-groups.
// S^T MFMA -> exp2 -> direct K=16 PV (no P roundtrip), ctx in-place over q.
// grid (2048/128, 32) = 512 blocks.
// ---------------------------------------------------------------------------
__global__ __launch_bounds__(256) void attn128(
    short* __restrict__ qkv, const short* __restrict__ vt)
{
    __shared__ short Ks[128 * 72];   // [key][dim]
    __shared__ short Vs[16 * 520];   // [g][dim][k&7], g = key>>3 (tile-local)

    const int tid  = threadIdx.x;
    const int lane = tid & 63;
    const int wave = tid >> 6;
    const int quad = lane >> 4;
    const int l16  = lane & 15;
    const int bh   = blockIdx.y, b = bh >> 4, h = bh & 15;
    const int qb   = blockIdx.x * 128;
    const size_t rowbase = (size_t)b * 2048;

    // Q fragments for 2 q-groups (B-op for S^T), pre-scaled by log2e/32
    short8 aq[2][2];
    #pragma unroll
    for (int qg = 0; qg < 2; ++qg) {
        const short* qp = qkv + (rowbase + qb + wave * 32 + qg * 16 + l16) * 3072 + h * 64;
        aq[qg][0] = *(const short8*)(qp + quad * 8);
        aq[qg][1] = *(const short8*)(qp + 32 + quad * 8);
    }

    f32x4 o[2][4];
    #pragma unroll
    for (int qg = 0; qg < 2; ++qg)
        #pragma unroll
        for (int c = 0; c < 4; ++c) o[qg][c] = f32x4{0.f, 0.f, 0.f, 0.f};
    float rsum[2] = {0.f, 0.f};   // softmax denom partials for q = l16

    const int kkey = tid >> 1, kdc = (tid & 1) * 32;
    const int vdim = tid >> 2, vg0 = (tid & 3) * 4;
    const short* kbase = qkv + (rowbase + kkey) * 3072 + 1024 + h * 64 + kdc;
    const short* vbase = vt + ((size_t)bh * 64 + vdim) * 2048 + vg0 * 8;

    // prefetch tile 0
    short8 kr0 = *(const short8*)(kbase);
    short8 kr1 = *(const short8*)(kbase + 8);
    short8 kr2 = *(const short8*)(kbase + 16);
    short8 kr3 = *(const short8*)(kbase + 24);
    short8 vr0 = *(const short8*)(vbase);
    short8 vr1 = *(const short8*)(vbase + 8);
    short8 vr2 = *(const short8*)(vbase + 16);
    short8 vr3 = *(const short8*)(vbase + 24);

    for (int kt = 0; kt < 2048; kt += 128) {
        __syncthreads();                      // prior-tile LDS readers done
        *(short8*)&Ks[kkey * 72 + kdc]      = kr0;
        *(short8*)&Ks[kkey * 72 + kdc + 8]  = kr1;
        *(short8*)&Ks[kkey * 72 + kdc + 16] = kr2;
        *(short8*)&Ks[kkey * 72 + kdc + 24] = kr3;
        *(short8*)&Vs[(vg0 + 0) * 520 + vdim * 8] = vr0;
        *(short8*)&Vs[(vg0 + 1) * 520 + vdim * 8] = vr1;
        *(short8*)&Vs[(vg0 + 2) * 520 + vdim * 8] = vr2;
        *(short8*)&Vs[(vg0 + 3) * 520 + vdim * 8] = vr3;
        if (kt + 128 < 2048) {                // prefetch next tile
            const short* kp = kbase + (size_t)(kt + 128) * 3072;
            kr0 = *(const short8*)(kp);
            kr1 = *(const short8*)(kp + 8);
            kr2 = *(const short8*)(kp + 16);
            kr3 = *(const short8*)(kp + 24);
            const short* vp = vbase + kt + 128;
            vr0 = *(const short8*)(vp);
            vr1 = *(const short8*)(vp + 8);
            vr2 = *(const short8*)(vp + 16);
            vr3 = *(const short8*)(vp + 24);
        }
        __syncthreads();                      // tile visible

        // two chunks of 64 keys: S^T -> exp2 -> PV
        #pragma unroll
        for (int cc = 0; cc < 2; ++cc) {
            // S^T: lane holds S[q=l16][key=(cc*4+c4)*16+quad*4+r], per q-group
            f32x4 st[2][4];
            #pragma unroll
            for (int c4 = 0; c4 < 4; ++c4) {
                const int c = cc * 4 + c4;
                short8 ka0 = *(const short8*)&Ks[(c * 16 + l16) * 72 + quad * 8];
                short8 ka1 = *(const short8*)&Ks[(c * 16 + l16) * 72 + 32 + quad * 8];
                #pragma unroll
                for (int qg = 0; qg < 2; ++qg) {
                    f32x4 z = f32x4{0.f, 0.f, 0.f, 0.f};
                    z = mfma_bf16(ka0, aq[qg][0], z);
                    st[qg][c4] = mfma_bf16(ka1, aq[qg][1], z);
                }
            }
            // p = exp2(s'): bare v_exp_f32 + v_cvt_pk_bf16_f32 packing
            uint2v pa[2][4];
            #pragma unroll
            for (int qg = 0; qg < 2; ++qg) {
                #pragma unroll
                for (int c4 = 0; c4 < 4; ++c4) {
                    float p0 = fexp2(st[qg][c4][0]);
                    float p1 = fexp2(st[qg][c4][1]);
                    float p2 = fexp2(st[qg][c4][2]);
                    float p3 = fexp2(st[qg][c4][3]);
                    rsum[qg] += (p0 + p1) + (p2 + p3);
                    uint2v pk;
                    pk[0] = pkbf(p0, p1);
                    pk[1] = pkbf(p2, p3);
                    pa[qg][c4] = pk;
                }
            }
            // PV: bv read once, used by both q-groups
            #pragma unroll
            for (int c2 = 0; c2 < 4; ++c2) {
                #pragma unroll
                for (int c4 = 0; c4 < 4; ++c4) {
                    const int c = cc * 4 + c4;
                    uint2v bv = *(const uint2v*)&Vs[(2 * c + (quad >> 1)) * 520
                                                    + (c2 * 16 + l16) * 8
                                                    + (quad & 1) * 4];
                    #pragma unroll
                    for (int qg = 0; qg < 2; ++qg)
                        o[qg][c2] = mfma16(pa[qg][c4], bv, o[qg][c2]);
                }
            }
        }
    }

    // full denom for q=l16: sum over the 4 quad-lanes
    #pragma unroll
    for (int qg = 0; qg < 2; ++qg) {
        rsum[qg] += __shfl_xor(rsum[qg], 16, 64);
        rsum[qg] += __shfl_xor(rsum[qg], 32, 64);
    }

    // epilogue: o rows are q=quad*4+r; fetch that q's denom from lane q
    #pragma unroll
    for (int qg = 0; qg < 2; ++qg) {
        #pragma unroll
        for (int r = 0; r < 4; ++r) {
            float inv = 1.0f / __shfl(rsum[qg], quad * 4 + r, 64);
            size_t row = rowbase + qb + wave * 32 + qg * 16 + quad * 4 + r;
            #pragma unroll
            for (int c2 = 0; c2 < 4; ++c2)
                qkv[row * 3072 + h * 64 + c2 * 16 + l16] = f2b(o[qg][c2][r] * inv);
        }
    }
}

// ---------------------------------------------------------------------------
extern "C" void kernel_launch(void* const* d_in, const int* in_sizes, int n_in,
                              void* d_out, int out_size, void* d_ws, size_t ws_size,
                              hipStream_t stream)
{
    const float* x    = (const float*)d_in[0];   // (2,2048,1024) fp32
    const float* Wqkv = (const float*)d_in[2];   // (1024,3072) fp32
    const float* Wout = (const float*)d_in[3];   // (1024,1024) fp32
    const float* bout = (const float*)d_in[4];   // (1024,) fp32
    float* out = (float*)d_out;                  // (2,2048,1024) fp32

    // ws: 32 MiB. qkv 24 MiB | 8 MiB region time-shared: Wqkvt -> vt -> Woutt
    // d_out doubles as scratch for xbf (first 8 MiB) until gemm2 overwrites.
    short* qkv    = (short*)d_ws;                // 4096 x 3072 bf16
    short* vtbuf  = qkv + (size_t)4096 * 3072;   // 8 MiB region
    short* wqkvt  = vtbuf;                       // 3072 x 1024 bf16
    short* woutt  = vtbuf;                       // 1024 x 1024 bf16
    short* xbf    = (short*)d_out;               // 4096 x 1024 bf16 (scratch)

    dim3 blk(256);
    cvt_bf16<<<dim3(2048), blk, 0, stream>>>(x, xbf);
    transpose_w<<<dim3(48, 16), blk, 0, stream>>>(Wqkv, wqkvt, 1024, 3072);
    gemm128<true, false, short><<<dim3(24, 32), blk, 0, stream>>>(
        xbf, wqkvt, nullptr, qkv, 4096, 3072, 1024, 1024);
    vtrans<<<dim3(32, 32), blk, 0, stream>>>(qkv, vtbuf);
    attn128<<<dim3(16, 32), blk, 0, stream>>>(qkv, vtbuf);
    transpose_w<<<dim3(16, 16), blk, 0, stream>>>(Wout, woutt, 1024, 1024);
    gemm128<false, true, float><<<dim3(8, 32), blk, 0, stream>>>(
        qkv, woutt, bout, out, 4096, 1024, 1024, 3072);
}